// Round 3
// baseline (979.633 us; speedup 1.0000x reference)
//
#include <hip/hip_runtime.h>

#define T_TOK 8192
#define DIM   1024
#define HDIM  4096
#define NE    8
#define BM 256
#define BN 256
#define BK 64
#define SLOT_CAP (T_TOK * 2 + NE * BM)   // 18432 = 72 * 256
#define TILES_M (SLOT_CAP / BM)          // 72
#define LDS_BYTES 131072

typedef float        f32x4 __attribute__((ext_vector_type(4)));
typedef unsigned int u32x4 __attribute__((ext_vector_type(4)));

__device__ inline unsigned short f2bf(float f) {
  union { float f; unsigned int u; } a; a.f = f;
  unsigned int u = a.u;
  unsigned int r = (u + 0x7FFFu + ((u >> 16) & 1u)) >> 16;  // RNE
  return (unsigned short)r;
}

__device__ inline f32x4 mfma_bf16_16x16x32(u32x4 a, u32x4 b, f32x4 c) {
  asm("v_mfma_f32_16x16x32_bf16 %0, %1, %2, %0" : "+v"(c) : "v"(a), "v"(b));
  return c;
}

__device__ inline void gload_lds16(const void* g, void* l) {
  __builtin_amdgcn_global_load_lds(
      (const __attribute__((address_space(1))) void*)g,
      (__attribute__((address_space(3))) void*)l, 16, 0, 0);
}

__device__ inline float gelu_tanh(float v) {
  const float c = 0.7978845608028654f;   // sqrt(2/pi)
  float t = tanhf(c * (v + 0.044715f * v * v * v));
  return 0.5f * v * (1.0f + t);
}

// ---- x fp32 -> bf16 -------------------------------------------------------
__global__ __launch_bounds__(256) void convert_x_kernel(const float* __restrict__ x,
                                                        unsigned short* __restrict__ xb) {
  size_t i = ((size_t)blockIdx.x * 256 + threadIdx.x) * 4;
  f32x4 v = *(const f32x4*)(x + i);
  unsigned long long p = (unsigned long long)f2bf(v[0])
                       | ((unsigned long long)f2bf(v[1]) << 16)
                       | ((unsigned long long)f2bf(v[2]) << 32)
                       | ((unsigned long long)f2bf(v[3]) << 48);
  *(unsigned long long*)(xb + i) = p;
}

// ---- per-expert transpose: src fp32 [E][R][C] -> dst bf16 [E][C][R] -------
__global__ __launch_bounds__(256) void transpose_bf16_kernel(const float* __restrict__ src,
                                                             unsigned short* __restrict__ dst,
                                                             int R, int C) {
  __shared__ float tile[64][65];
  int e  = blockIdx.z;
  int c0 = blockIdx.x * 64, r0 = blockIdx.y * 64;
  int c  = threadIdx.x & 63, r4 = threadIdx.x >> 6;
  const float* s = src + (size_t)e * R * C;
#pragma unroll
  for (int i = 0; i < 16; i++) {
    int r = r4 + i * 4;
    tile[r][c] = s[(size_t)(r0 + r) * C + (c0 + c)];
  }
  __syncthreads();
  int cc = (threadIdx.x & 31) * 2;
  int rb = threadIdx.x >> 5;
  unsigned short* d = dst + (size_t)e * R * C;
#pragma unroll
  for (int i = 0; i < 8; i++) {
    int rr = rb + i * 8;
    unsigned int p = (unsigned int)f2bf(tile[cc][rr])
                   | ((unsigned int)f2bf(tile[cc + 1][rr]) << 16);
    *(unsigned int*)(d + (size_t)(c0 + rr) * R + (r0 + cc)) = p;
  }
}

// ---- routing: logits, top-2, weights, counts ------------------------------
__global__ __launch_bounds__(256) void routing_kernel(const float* __restrict__ x,
                                                      const float* __restrict__ Wg,
                                                      int* __restrict__ tok_e,
                                                      float* __restrict__ tok_w,
                                                      int* __restrict__ counts) {
  int tok  = (blockIdx.x * 256 + threadIdx.x) >> 6;
  int lane = threadIdx.x & 63;
  const float* xr = x + (size_t)tok * DIM;
  float acc[NE];
#pragma unroll
  for (int e = 0; e < NE; e++) acc[e] = 0.f;
  for (int d = lane; d < DIM; d += 64) {
    float xv = xr[d];
    const float* wr = Wg + d * NE;
#pragma unroll
    for (int e = 0; e < NE; e++) acc[e] += xv * wr[e];
  }
#pragma unroll
  for (int e = 0; e < NE; e++) {
#pragma unroll
    for (int off = 32; off > 0; off >>= 1) acc[e] += __shfl_xor(acc[e], off);
  }
  if (lane == 0) {
    int i0 = 0;
#pragma unroll
    for (int e = 1; e < NE; e++) if (acc[e] > acc[i0]) i0 = e;
    int i1 = (i0 == 0) ? 1 : 0;
#pragma unroll
    for (int e = 0; e < NE; e++) if (e != i0 && acc[e] > acc[i1]) i1 = e;
    float w0 = 1.0f / (1.0f + expf(acc[i1] - acc[i0]));
    float w1 = 1.0f - w0;
    tok_e[tok * 2]     = i0;
    tok_e[tok * 2 + 1] = i1;
    tok_w[tok * 2]     = w0;
    tok_w[tok * 2 + 1] = w1;
    atomicAdd(&counts[i0], 1);
    atomicAdd(&counts[i1], 1);
  }
}

// ---- padded (256-aligned) segment offsets ---------------------------------
__global__ void offsets_kernel(const int* __restrict__ counts, int* __restrict__ offs) {
  if (threadIdx.x == 0 && blockIdx.x == 0) {
    int acc = 0; offs[0] = 0;
    for (int e = 0; e < NE; e++) {
      acc += (counts[e] + BM - 1) / BM * BM;
      offs[e + 1] = acc;
    }
  }
}

// ---- scatter token ids into expert segments -------------------------------
__global__ __launch_bounds__(256) void scatter_kernel(const int* __restrict__ tok_e,
                                                      const float* __restrict__ tok_w,
                                                      const int* __restrict__ offs,
                                                      int* __restrict__ cursors,
                                                      int* __restrict__ slot_token,
                                                      float* __restrict__ slot_w) {
  int t = blockIdx.x * 256 + threadIdx.x;
#pragma unroll
  for (int j = 0; j < 2; j++) {
    int e = tok_e[t * 2 + j];
    int pos = atomicAdd(&cursors[e], 1);
    int s = offs[e] + pos;
    slot_token[s] = t;
    slot_w[s] = tok_w[t * 2 + j];
  }
}

// ===========================================================================
// 8-phase 256x256 GEMM core (m201 template, plain HIP):
//  - 512 thr = 8 waves (2M x 4N); wave out 128x64; acc 8x4 f32x4.
//  - LDS 128KB: A[2][256][64], B[2][256][64] bf16; linear rows; XOR swizzle
//    baked into the GLOBAL source chunk ((l&7)^(row&7)); ds_read swizzles
//    chunk = (kk*4 + lane>>4) ^ (lane&7).  (both-sides-or-neither, rule #21)
//  - per K-tile 4 phases: {ds-reads | stage | barrier | setprio+16 MFMA | barrier}
//    q0 reads all B (8) + A m0-1 (4); q1..q3 read A pairs (4 each).
//  - stage stagger: q0: A(t+1)h0, q1: A(t+1)h1 + B(t+2)h0, q2: B(t+2)h1.
//    Regions: B[b] last read q0, A[b] last read q3 -> no overwrite race.
//  - boundary (q3): s_waitcnt vmcnt(4)  (counted: B(t+2) stays in flight).
// ===========================================================================

#define GEMM_CORE(NT_, A_EPILOG_UNUSED)                                         \
  f32x4 acc[8][4];                                                              \
  _Pragma("unroll") for (int m = 0; m < 8; m++)                                 \
  _Pragma("unroll") for (int n = 0; n < 4; n++) acc[m][n] = 0.f;                \
  /* prologue: A(0), B(0) -> buf0 ; B(1) -> buf1 */                             \
  _Pragma("unroll") for (int i = 0; i < 4; i++) {                               \
    gload_lds16(aSrc[i], ldsA + (((i >> 1) * 128 + (i & 1) * 64 + w * 8)) * 64);\
    aSrc[i] += BK;                                                              \
  }                                                                             \
  _Pragma("unroll") for (int i = 0; i < 4; i++) {                               \
    gload_lds16(bSrc[i], ldsB + (((i >> 1) * 128 + (i & 1) * 64 + w * 8)) * 64);\
    bSrc[i] += BK;                                                              \
  }                                                                             \
  _Pragma("unroll") for (int i = 0; i < 4; i++) {                               \
    gload_lds16(bSrc[i], ldsB + 16384 + (((i >> 1) * 128 + (i & 1) * 64 + w * 8)) * 64); \
    bSrc[i] += BK;                                                              \
  }                                                                             \
  asm volatile("s_waitcnt vmcnt(4)" ::: "memory");                              \
  __builtin_amdgcn_s_barrier();                                                 \
  for (int t = 0; t < (NT_); ++t) {                                             \
    const unsigned short* At = ldsA + (t & 1) * 16384;                          \
    const unsigned short* Bt = ldsB + (t & 1) * 16384;                          \
    unsigned short* An = ldsA + ((t + 1) & 1) * 16384;                          \
    unsigned short* B2 = ldsB + (t & 1) * 16384;                                \
    u32x4 breg[4][2], areg[2][2];                                               \
    _Pragma("unroll") for (int q = 0; q < 4; ++q) {                             \
      if (q == 0) {                                                             \
        _Pragma("unroll") for (int n = 0; n < 4; n++) {                         \
          breg[n][0] = *(const u32x4*)(Bt + boff[n] + ck0);                     \
          breg[n][1] = *(const u32x4*)(Bt + boff[n] + ck1);                     \
        }                                                                       \
      }                                                                         \
      _Pragma("unroll") for (int mm = 0; mm < 2; mm++) {                        \
        areg[mm][0] = *(const u32x4*)(At + aoff[q * 2 + mm] + ck0);             \
        areg[mm][1] = *(const u32x4*)(At + aoff[q * 2 + mm] + ck1);             \
      }                                                                         \
      if (q == 0) {                                                             \
        if (t + 1 < (NT_)) {                                                    \
          _Pragma("unroll") for (int i = 0; i < 2; i++) {                       \
            gload_lds16(aSrc[i], An + ((i & 1) * 64 + w * 8) * 64);             \
            aSrc[i] += BK;                                                      \
          }                                                                     \
        }                                                                       \
      } else if (q == 1) {                                                      \
        if (t + 1 < (NT_)) {                                                    \
          _Pragma("unroll") for (int i = 2; i < 4; i++) {                       \
            gload_lds16(aSrc[i], An + (128 + (i & 1) * 64 + w * 8) * 64);       \
            aSrc[i] += BK;                                                      \
          }                                                                     \
        }                                                                       \
        __builtin_amdgcn_sched_barrier(0);                                      \
        if (t + 2 < (NT_)) {                                                    \
          _Pragma("unroll") for (int i = 0; i < 2; i++) {                       \
            gload_lds16(bSrc[i], B2 + ((i & 1) * 64 + w * 8) * 64);             \
            bSrc[i] += BK;                                                      \
          }                                                                     \
        }                                                                       \
      } else if (q == 2) {                                                      \
        if (t + 2 < (NT_)) {                                                    \
          _Pragma("unroll") for (int i = 2; i < 4; i++) {                       \
            gload_lds16(bSrc[i], B2 + (128 + (i & 1) * 64 + w * 8) * 64);       \
            bSrc[i] += BK;                                                      \
          }                                                                     \
        }                                                                       \
      }                                                                         \
      __builtin_amdgcn_s_barrier();                                             \
      __builtin_amdgcn_s_setprio(1);                                            \
      _Pragma("unroll") for (int mm = 0; mm < 2; mm++)                          \
        _Pragma("unroll") for (int n = 0; n < 4; n++) {                         \
          acc[q * 2 + mm][n] = mfma_bf16_16x16x32(areg[mm][0], breg[n][0], acc[q * 2 + mm][n]); \
          acc[q * 2 + mm][n] = mfma_bf16_16x16x32(areg[mm][1], breg[n][1], acc[q * 2 + mm][n]); \
        }                                                                       \
      __builtin_amdgcn_s_setprio(0);                                            \
      if (q == 3 && t < (NT_) - 1) {                                            \
        if (t == (NT_) - 2) asm volatile("s_waitcnt vmcnt(0)" ::: "memory");    \
        else                asm volatile("s_waitcnt vmcnt(4)" ::: "memory");    \
      }                                                                         \
      __builtin_amdgcn_s_barrier();                                             \
    }                                                                           \
  }

// ---- GEMM1: h = gelu(x_gathered @ W1T[e] + b1[e]); h bf16 [SLOT_CAP][H] ---
__global__ __launch_bounds__(512, 2) void gemm1_kernel(const unsigned short* __restrict__ Xb,
                                                       const unsigned short* __restrict__ W1T,
                                                       const float* __restrict__ b1,
                                                       const int* __restrict__ slot_token,
                                                       const int* __restrict__ offs,
                                                       unsigned short* __restrict__ Hbuf) {
  extern __shared__ __align__(16) unsigned short smem[];
  unsigned short* ldsA = smem;               // [2][256][64]
  unsigned short* ldsB = smem + 2 * 256 * 64;
  int row0 = blockIdx.x * BM;
  if (row0 >= offs[NE]) return;
  int e = 0;
#pragma unroll
  for (int i = 1; i < NE; i++) if (row0 >= offs[i]) e = i;
  int n0 = blockIdx.y * BN;
  int tid = threadIdx.x, lane = tid & 63, w = tid >> 6;
  int wr = w >> 2, wc = w & 3;

  int rg = tid >> 3;
  int cg = (tid & 7) ^ (rg & 7);
  const unsigned short* aSrc[4];
  const unsigned short* bSrc[4];
#pragma unroll
  for (int i = 0; i < 4; i++) {
    int ar = (i >> 1) * 128 + (i & 1) * 64 + rg;
    int tk = slot_token[row0 + ar]; if (tk < 0) tk = 0;
    aSrc[i] = Xb + (size_t)tk * DIM + cg * 8;
    bSrc[i] = W1T + ((size_t)e * HDIM + n0 + ar) * DIM + cg * 8;
  }
  int frow = lane & 15, hi = lane >> 4;
  int ck0 = ((0 + hi) ^ (lane & 7)) * 8;
  int ck1 = ((4 + hi) ^ (lane & 7)) * 8;
  int aoff[8], boff[4];
#pragma unroll
  for (int m = 0; m < 8; m++) aoff[m] = (wr * 128 + m * 16 + frow) * 64;
#pragma unroll
  for (int n = 0; n < 4; n++) boff[n] = (wc * 64 + n * 16 + frow) * 64;

  GEMM_CORE(16, )

  int rb = hi * 4;
#pragma unroll
  for (int n = 0; n < 4; n++) {
    int col = n0 + wc * 64 + n * 16 + frow;
    float bias = b1[e * HDIM + col];
#pragma unroll
    for (int m = 0; m < 8; m++) {
#pragma unroll
      for (int j = 0; j < 4; j++) {
        int gr = row0 + wr * 128 + m * 16 + rb + j;
        float v = acc[m][n][j] + bias;
        Hbuf[(size_t)gr * HDIM + col] = f2bf(gelu_tanh(v));
      }
    }
  }
}

// ---- GEMM2 (split-K=4): out[token] += w * (h @ W2T[e] + b2[e]) ------------
__global__ __launch_bounds__(512, 2) void gemm2_kernel(const unsigned short* __restrict__ Hbuf,
                                                       const unsigned short* __restrict__ W2T,
                                                       const float* __restrict__ b2,
                                                       const int* __restrict__ slot_token,
                                                       const float* __restrict__ slot_w,
                                                       const int* __restrict__ offs,
                                                       float* __restrict__ out) {
  extern __shared__ __align__(16) unsigned short smem[];
  unsigned short* ldsA = smem;
  unsigned short* ldsB = smem + 2 * 256 * 64;
  int row0 = blockIdx.x * BM;
  if (row0 >= offs[NE]) return;
  int e = 0;
#pragma unroll
  for (int i = 1; i < NE; i++) if (row0 >= offs[i]) e = i;
  int n0 = blockIdx.y * BN;
  int split = blockIdx.z;
  int kbase = split * (HDIM / 4);
  int tid = threadIdx.x, lane = tid & 63, w = tid >> 6;
  int wr = w >> 2, wc = w & 3;

  int rg = tid >> 3;
  int cg = (tid & 7) ^ (rg & 7);
  const unsigned short* aSrc[4];
  const unsigned short* bSrc[4];
#pragma unroll
  for (int i = 0; i < 4; i++) {
    int ar = (i >> 1) * 128 + (i & 1) * 64 + rg;
    aSrc[i] = Hbuf + (size_t)(row0 + ar) * HDIM + kbase + cg * 8;
    bSrc[i] = W2T + ((size_t)e * DIM + n0 + ar) * HDIM + kbase + cg * 8;
  }
  int frow = lane & 15, hi = lane >> 4;
  int ck0 = ((0 + hi) ^ (lane & 7)) * 8;
  int ck1 = ((4 + hi) ^ (lane & 7)) * 8;
  int aoff[8], boff[4];
#pragma unroll
  for (int m = 0; m < 8; m++) aoff[m] = (wr * 128 + m * 16 + frow) * 64;
#pragma unroll
  for (int n = 0; n < 4; n++) boff[n] = (wc * 64 + n * 16 + frow) * 64;

  GEMM_CORE(16, )

  int rb = hi * 4;
  float bias[4];
#pragma unroll
  for (int n = 0; n < 4; n++)
    bias[n] = (split == 0) ? b2[e * DIM + n0 + wc * 64 + n * 16 + frow] : 0.f;
#pragma unroll
  for (int m = 0; m < 8; m++) {
#pragma unroll
    for (int j = 0; j < 4; j++) {
      int gr = row0 + wr * 128 + m * 16 + rb + j;
      int tk = slot_token[gr];
      if (tk < 0) continue;
      float wgt = slot_w[gr];
#pragma unroll
      for (int n = 0; n < 4; n++) {
        int col = n0 + wc * 64 + n * 16 + frow;
        atomicAdd(out + (size_t)tk * DIM + col, (acc[m][n][j] + bias[n]) * wgt);
      }
    }
  }
}

extern "C" void kernel_launch(void* const* d_in, const int* in_sizes, int n_in,
                              void* d_out, int out_size, void* d_ws, size_t ws_size,
                              hipStream_t stream) {
  (void)in_sizes; (void)n_in;
  const float* x  = (const float*)d_in[0];
  const float* Wg = (const float*)d_in[1];
  const float* W1 = (const float*)d_in[2];
  const float* b1 = (const float*)d_in[3];
  const float* W2 = (const float*)d_in[4];
  const float* b2 = (const float*)d_in[5];
  float* out = (float*)d_out;

  char* ws = (char*)d_ws;
  size_t off = 0;
  auto take = [&](size_t bytes) -> char* {
    char* p = ws + off;
    off += (bytes + 255) & ~(size_t)255;
    return p;
  };
  unsigned short* W1T  = (unsigned short*)take((size_t)NE * DIM * HDIM * 2);
  unsigned short* W2T  = (unsigned short*)take((size_t)NE * DIM * HDIM * 2);
  unsigned short* Xb   = (unsigned short*)take((size_t)T_TOK * DIM * 2);
  unsigned short* Hbuf = (unsigned short*)take((size_t)SLOT_CAP * HDIM * 2);
  int*   slot_token = (int*)take(SLOT_CAP * 4);
  float* slot_w     = (float*)take(SLOT_CAP * 4);
  int*   tok_e      = (int*)take(T_TOK * 2 * 4);
  float* tok_w      = (float*)take(T_TOK * 2 * 4);
  int*   counts     = (int*)take(256);
  int*   cursors    = (int*)take(256);
  int*   offs       = (int*)take(256);

  if (off > ws_size) {
    hipMemsetAsync(d_out, 0, (size_t)out_size * 4, stream);
    return;
  }

  // allow 128 KB dynamic LDS (host-side, capture-safe, idempotent)
  hipFuncSetAttribute((const void*)gemm1_kernel,
                      hipFuncAttributeMaxDynamicSharedMemorySize, LDS_BYTES);
  hipFuncSetAttribute((const void*)gemm2_kernel,
                      hipFuncAttributeMaxDynamicSharedMemorySize, LDS_BYTES);

  hipMemsetAsync(counts, 0, 256, stream);
  hipMemsetAsync(cursors, 0, 256, stream);
  hipMemsetAsync(slot_token, 0xFF, SLOT_CAP * 4, stream);
  hipMemsetAsync(out, 0, (size_t)out_size * 4, stream);

  convert_x_kernel<<<T_TOK * DIM / 1024, 256, 0, stream>>>(x, Xb);
  transpose_bf16_kernel<<<dim3(HDIM / 64, DIM / 64, NE), 256, 0, stream>>>(W1, W1T, DIM, HDIM);
  transpose_bf16_kernel<<<dim3(DIM / 64, HDIM / 64, NE), 256, 0, stream>>>(W2, W2T, HDIM, DIM);
  routing_kernel<<<T_TOK / 4, 256, 0, stream>>>(x, Wg, tok_e, tok_w, counts);
  offsets_kernel<<<1, 64, 0, stream>>>(counts, offs);
  scatter_kernel<<<T_TOK / 256, 256, 0, stream>>>(tok_e, tok_w, offs, cursors, slot_token, slot_w);
  gemm1_kernel<<<dim3(TILES_M, HDIM / BN), 512, LDS_BYTES, stream>>>(Xb, W1T, b1, slot_token, offs, Hbuf);
  gemm2_kernel<<<dim3(TILES_M, DIM / BN, 4), 512, LDS_BYTES, stream>>>(Hbuf, W2T, b2, slot_token, slot_w, offs, out);
}

// Round 4
// 767.183 us; speedup vs baseline: 1.2769x; 1.2769x over previous
//
#include <hip/hip_runtime.h>

#define T_TOK 8192
#define DIM   1024
#define HDIM  4096
#define NE    8
#define SLOT_CAP 17408   // 16384 pairs + 8*128 padding, = 136 * 128
#define TILES_MAX 136
#define BM 128
#define BN 128
#define BK 64

typedef float        f32x4 __attribute__((ext_vector_type(4)));
typedef unsigned int u32x4 __attribute__((ext_vector_type(4)));

__device__ inline unsigned short f2bf(float f) {
  union { float f; unsigned int u; } a; a.f = f;
  unsigned int u = a.u;
  unsigned int r = (u + 0x7FFFu + ((u >> 16) & 1u)) >> 16;  // RNE
  return (unsigned short)r;
}

__device__ inline f32x4 mfma_bf16_16x16x32(u32x4 a, u32x4 b, f32x4 c) {
  asm("v_mfma_f32_16x16x32_bf16 %0, %1, %2, %0" : "+v"(c) : "v"(a), "v"(b));
  return c;
}

__device__ inline void gload_lds16(const void* g, void* l) {
  __builtin_amdgcn_global_load_lds(
      (const __attribute__((address_space(1))) void*)g,
      (__attribute__((address_space(3))) void*)l, 16, 0, 0);
}

// gelu(v) = v * sigmoid(2*c*(v + 0.044715 v^3))  (tanh-form identity)
__device__ inline float gelu_fast(float v) {
  const float c2 = 1.5957691216057308f;   // 2*sqrt(2/pi)
  float z = c2 * (v + 0.044715f * v * v * v);
  return v / (1.0f + __expf(-z));
}

// ---- x fp32 -> bf16 -------------------------------------------------------
__global__ __launch_bounds__(256) void convert_x_kernel(const float* __restrict__ x,
                                                        unsigned short* __restrict__ xb) {
  size_t i = ((size_t)blockIdx.x * 256 + threadIdx.x) * 4;
  f32x4 v = *(const f32x4*)(x + i);
  unsigned long long p = (unsigned long long)f2bf(v[0])
                       | ((unsigned long long)f2bf(v[1]) << 16)
                       | ((unsigned long long)f2bf(v[2]) << 32)
                       | ((unsigned long long)f2bf(v[3]) << 48);
  *(unsigned long long*)(xb + i) = p;
}

// ---- per-expert transpose: src fp32 [E][R][C] -> dst bf16 [E][C][R] -------
__global__ __launch_bounds__(256) void transpose_bf16_kernel(const float* __restrict__ src,
                                                             unsigned short* __restrict__ dst,
                                                             int R, int C) {
  __shared__ float tile[64][65];
  int e  = blockIdx.z;
  int c0 = blockIdx.x * 64, r0 = blockIdx.y * 64;
  int c  = threadIdx.x & 63, r4 = threadIdx.x >> 6;
  const float* s = src + (size_t)e * R * C;
#pragma unroll
  for (int i = 0; i < 16; i++) {
    int r = r4 + i * 4;
    tile[r][c] = s[(size_t)(r0 + r) * C + (c0 + c)];
  }
  __syncthreads();
  int cc = (threadIdx.x & 31) * 2;
  int rb = threadIdx.x >> 5;
  unsigned short* d = dst + (size_t)e * R * C;
#pragma unroll
  for (int i = 0; i < 8; i++) {
    int rr = rb + i * 8;
    unsigned int p = (unsigned int)f2bf(tile[cc][rr])
                   | ((unsigned int)f2bf(tile[cc + 1][rr]) << 16);
    *(unsigned int*)(d + (size_t)(c0 + rr) * R + (r0 + cc)) = p;
  }
}

// ---- routing: logits, top-2, weights, counts ------------------------------
__global__ __launch_bounds__(256) void routing_kernel(const float* __restrict__ x,
                                                      const float* __restrict__ Wg,
                                                      int* __restrict__ tok_e,
                                                      float* __restrict__ tok_w,
                                                      int* __restrict__ counts) {
  int tok  = (blockIdx.x * 256 + threadIdx.x) >> 6;
  int lane = threadIdx.x & 63;
  const float* xr = x + (size_t)tok * DIM;
  float acc[NE];
#pragma unroll
  for (int e = 0; e < NE; e++) acc[e] = 0.f;
  for (int d = lane; d < DIM; d += 64) {
    float xv = xr[d];
    const float* wr = Wg + d * NE;
#pragma unroll
    for (int e = 0; e < NE; e++) acc[e] += xv * wr[e];
  }
#pragma unroll
  for (int e = 0; e < NE; e++) {
#pragma unroll
    for (int off = 32; off > 0; off >>= 1) acc[e] += __shfl_xor(acc[e], off);
  }
  if (lane == 0) {
    int i0 = 0;
#pragma unroll
    for (int e = 1; e < NE; e++) if (acc[e] > acc[i0]) i0 = e;
    int i1 = (i0 == 0) ? 1 : 0;
#pragma unroll
    for (int e = 0; e < NE; e++) if (e != i0 && acc[e] > acc[i1]) i1 = e;
    float w0 = 1.0f / (1.0f + expf(acc[i1] - acc[i0]));
    float w1 = 1.0f - w0;
    tok_e[tok * 2]     = i0;
    tok_e[tok * 2 + 1] = i1;
    tok_w[tok * 2]     = w0;
    tok_w[tok * 2 + 1] = w1;
    atomicAdd(&counts[i0], 1);
    atomicAdd(&counts[i1], 1);
  }
}

// ---- padded (128-aligned) segment offsets ---------------------------------
__global__ void offsets_kernel(const int* __restrict__ counts, int* __restrict__ offs) {
  if (threadIdx.x == 0 && blockIdx.x == 0) {
    int acc = 0; offs[0] = 0;
    for (int e = 0; e < NE; e++) {
      acc += (counts[e] + BM - 1) / BM * BM;
      offs[e + 1] = acc;
    }
  }
}

// ---- scatter token ids into expert segments; record token->slot map -------
__global__ __launch_bounds__(256) void scatter_kernel(const int* __restrict__ tok_e,
                                                      const int* __restrict__ offs,
                                                      int* __restrict__ cursors,
                                                      int* __restrict__ slot_token,
                                                      int* __restrict__ tok_slot) {
  int t = blockIdx.x * 256 + threadIdx.x;
#pragma unroll
  for (int j = 0; j < 2; j++) {
    int e = tok_e[t * 2 + j];
    int pos = atomicAdd(&cursors[e], 1);
    int s = offs[e] + pos;
    slot_token[s] = t;
    tok_slot[t * 2 + j] = s;
  }
}

// ===========================================================================
// GEMM core (m97 structure): 128x128 tile, BK=64, 4 waves, global_load_lds
// width 16 into LINEAR [128][64] bf16 LDS, XOR swizzle baked into the GLOBAL
// source chunk ((l&7)^(l>>3)); ds_read swizzles chunk with (lane&7).
// Verified round 2: SQ_LDS_BANK_CONFLICT == 0.
// XCD-aware block swizzle (T1): hw block h on XCD h%8 gets work (h%8)*cpx+h/8.
// ===========================================================================

// ---- GEMM1: h = gelu(x_gathered @ W1T[e] + b1[e]); h bf16 [SLOT_CAP][H] ---
__global__ __launch_bounds__(256) void gemm1_kernel(const unsigned short* __restrict__ Xb,
                                                    const unsigned short* __restrict__ W1T,
                                                    const float* __restrict__ b1,
                                                    const int* __restrict__ slot_token,
                                                    const int* __restrict__ offs,
                                                    unsigned short* __restrict__ Hbuf) {
  __shared__ __align__(16) unsigned short As[BM][BK];
  __shared__ __align__(16) unsigned short Bs[BN][BK];
  // XCD swizzle over linearized grid (gridX*gridY % 8 == 0)
  int gx = gridDim.x;
  int lin = blockIdx.y * gx + blockIdx.x;
  int cpx = (gx * gridDim.y) >> 3;
  int wk  = (lin & 7) * cpx + (lin >> 3);
  int bx = wk % gx, by = wk / gx;

  int row0 = bx * BM;
  if (row0 >= offs[NE]) return;
  int e = 0;
#pragma unroll
  for (int i = 1; i < NE; i++) if (row0 >= offs[i]) e = i;
  int n0  = by * BN;
  int tid  = threadIdx.x;
  int lane = tid & 63;
  int w    = tid >> 6;
  int wr = tid >> 7;
  int wc = (tid >> 6) & 1;

  int lr  = lane >> 3;
  int lcx = (lane & 7) ^ lr;
  const unsigned short* aG[4];
  const unsigned short* bG[4];
  unsigned short* aL[4];
  unsigned short* bL[4];
#pragma unroll
  for (int i = 0; i < 4; i++) {
    int r = w * 32 + i * 8;
    int tk = slot_token[row0 + r + lr];
    if (tk < 0) tk = 0;
    aG[i] = Xb + (size_t)tk * DIM + lcx * 8;
    bG[i] = W1T + ((size_t)e * HDIM + n0 + r + lr) * DIM + lcx * 8;
    aL[i] = &As[r][0];
    bL[i] = &Bs[r][0];
  }

  int frow = lane & 15;
  int kxs  = ((lane >> 4) * 8) ^ ((lane & 7) << 3);

  f32x4 acc[4][4];
#pragma unroll
  for (int m = 0; m < 4; m++)
#pragma unroll
    for (int n = 0; n < 4; n++) acc[m][n] = 0.f;

  for (int k0 = 0; k0 < DIM; k0 += BK) {
#pragma unroll
    for (int i = 0; i < 4; i++) gload_lds16(aG[i] + k0, aL[i]);
#pragma unroll
    for (int i = 0; i < 4; i++) gload_lds16(bG[i] + k0, bL[i]);
    __syncthreads();
#pragma unroll
    for (int kk = 0; kk < 2; kk++) {
      int col = (kk * 32) ^ kxs;
      u32x4 a[4], b[4];
#pragma unroll
      for (int m = 0; m < 4; m++)
        a[m] = *(const u32x4*)&As[wr * 64 + m * 16 + frow][col];
#pragma unroll
      for (int n = 0; n < 4; n++)
        b[n] = *(const u32x4*)&Bs[wc * 64 + n * 16 + frow][col];
#pragma unroll
      for (int m = 0; m < 4; m++)
#pragma unroll
        for (int n = 0; n < 4; n++)
          acc[m][n] = mfma_bf16_16x16x32(a[m], b[n], acc[m][n]);
    }
    __syncthreads();
  }

  int rbase = (lane >> 4) * 4;
  int cbase = lane & 15;
#pragma unroll
  for (int m = 0; m < 4; m++) {
#pragma unroll
    for (int n = 0; n < 4; n++) {
      int hcol = n0 + wc * 64 + n * 16 + cbase;
      float bias = b1[e * HDIM + hcol];
#pragma unroll
      for (int j = 0; j < 4; j++) {
        int gr = row0 + wr * 64 + m * 16 + rbase + j;
        float v = acc[m][n][j] + bias;
        Hbuf[(size_t)gr * HDIM + hcol] = f2bf(gelu_fast(v));
      }
    }
  }
}

// ---- GEMM2: Y[slot] = h @ W2T[e] + b2[e]  (no atomics, coalesced stores) --
__global__ __launch_bounds__(256) void gemm2_kernel(const unsigned short* __restrict__ Hbuf,
                                                    const unsigned short* __restrict__ W2T,
                                                    const float* __restrict__ b2,
                                                    const int* __restrict__ offs,
                                                    float* __restrict__ Ybuf) {
  __shared__ __align__(16) unsigned short As[BM][BK];
  __shared__ __align__(16) unsigned short Bs[BN][BK];
  int gx = gridDim.x;
  int lin = blockIdx.y * gx + blockIdx.x;
  int cpx = (gx * gridDim.y) >> 3;
  int wk  = (lin & 7) * cpx + (lin >> 3);
  int bx = wk % gx, by = wk / gx;

  int row0 = bx * BM;
  if (row0 >= offs[NE]) return;
  int e = 0;
#pragma unroll
  for (int i = 1; i < NE; i++) if (row0 >= offs[i]) e = i;
  int n0  = by * BN;
  int tid  = threadIdx.x;
  int lane = tid & 63;
  int w    = tid >> 6;
  int wr = tid >> 7;
  int wc = (tid >> 6) & 1;

  int lr  = lane >> 3;
  int lcx = (lane & 7) ^ lr;
  const unsigned short* aG[4];
  const unsigned short* bG[4];
  unsigned short* aL[4];
  unsigned short* bL[4];
#pragma unroll
  for (int i = 0; i < 4; i++) {
    int r = w * 32 + i * 8;
    aG[i] = Hbuf + (size_t)(row0 + r + lr) * HDIM + lcx * 8;
    bG[i] = W2T + ((size_t)e * DIM + n0 + r + lr) * HDIM + lcx * 8;
    aL[i] = &As[r][0];
    bL[i] = &Bs[r][0];
  }

  int frow = lane & 15;
  int kxs  = ((lane >> 4) * 8) ^ ((lane & 7) << 3);

  f32x4 acc[4][4];
#pragma unroll
  for (int m = 0; m < 4; m++)
#pragma unroll
    for (int n = 0; n < 4; n++) acc[m][n] = 0.f;

  for (int k0 = 0; k0 < HDIM; k0 += BK) {
#pragma unroll
    for (int i = 0; i < 4; i++) gload_lds16(aG[i] + k0, aL[i]);
#pragma unroll
    for (int i = 0; i < 4; i++) gload_lds16(bG[i] + k0, bL[i]);
    __syncthreads();
#pragma unroll
    for (int kk = 0; kk < 2; kk++) {
      int col = (kk * 32) ^ kxs;
      u32x4 a[4], b[4];
#pragma unroll
      for (int m = 0; m < 4; m++)
        a[m] = *(const u32x4*)&As[wr * 64 + m * 16 + frow][col];
#pragma unroll
      for (int n = 0; n < 4; n++)
        b[n] = *(const u32x4*)&Bs[wc * 64 + n * 16 + frow][col];
#pragma unroll
      for (int m = 0; m < 4; m++)
#pragma unroll
        for (int n = 0; n < 4; n++)
          acc[m][n] = mfma_bf16_16x16x32(a[m], b[n], acc[m][n]);
    }
    __syncthreads();
  }

  int rbase = (lane >> 4) * 4;
  int cbase = lane & 15;
#pragma unroll
  for (int m = 0; m < 4; m++) {
#pragma unroll
    for (int n = 0; n < 4; n++) {
      int dcol = n0 + wc * 64 + n * 16 + cbase;
      float bias = b2[e * DIM + dcol];
#pragma unroll
      for (int j = 0; j < 4; j++) {
        int gr = row0 + wr * 64 + m * 16 + rbase + j;
        Ybuf[(size_t)gr * DIM + dcol] = acc[m][n][j] + bias;
      }
    }
  }
}

// ---- combine: out[t] = w0*Y[s0] + w1*Y[s1] --------------------------------
__global__ __launch_bounds__(256) void combine_kernel(const float* __restrict__ Ybuf,
                                                      const int* __restrict__ tok_slot,
                                                      const float* __restrict__ tok_w,
                                                      float* __restrict__ out) {
  int t = blockIdx.x;
  int c = threadIdx.x * 4;
  int s0 = tok_slot[t * 2], s1 = tok_slot[t * 2 + 1];
  float w0 = tok_w[t * 2], w1 = tok_w[t * 2 + 1];
  f32x4 y0 = *(const f32x4*)(Ybuf + (size_t)s0 * DIM + c);
  f32x4 y1 = *(const f32x4*)(Ybuf + (size_t)s1 * DIM + c);
  f32x4 r;
#pragma unroll
  for (int i = 0; i < 4; i++) r[i] = w0 * y0[i] + w1 * y1[i];
  *(f32x4*)(out + (size_t)t * DIM + c) = r;
}

extern "C" void kernel_launch(void* const* d_in, const int* in_sizes, int n_in,
                              void* d_out, int out_size, void* d_ws, size_t ws_size,
                              hipStream_t stream) {
  (void)in_sizes; (void)n_in; (void)out_size;
  const float* x  = (const float*)d_in[0];
  const float* Wg = (const float*)d_in[1];
  const float* W1 = (const float*)d_in[2];
  const float* b1 = (const float*)d_in[3];
  const float* W2 = (const float*)d_in[4];
  const float* b2 = (const float*)d_in[5];
  float* out = (float*)d_out;

  char* ws = (char*)d_ws;
  size_t off = 0;
  auto take = [&](size_t bytes) -> char* {
    char* p = ws + off;
    off += (bytes + 255) & ~(size_t)255;
    return p;
  };
  unsigned short* W1T  = (unsigned short*)take((size_t)NE * DIM * HDIM * 2);
  unsigned short* W2T  = (unsigned short*)take((size_t)NE * DIM * HDIM * 2);
  unsigned short* Xb   = (unsigned short*)take((size_t)T_TOK * DIM * 2);
  unsigned short* Hbuf = (unsigned short*)take((size_t)SLOT_CAP * HDIM * 2);
  float* Ybuf       = (float*)take((size_t)SLOT_CAP * DIM * 4);
  int*   slot_token = (int*)take(SLOT_CAP * 4);
  int*   tok_e      = (int*)take(T_TOK * 2 * 4);
  float* tok_w      = (float*)take(T_TOK * 2 * 4);
  int*   tok_slot   = (int*)take(T_TOK * 2 * 4);
  int*   counts     = (int*)take(256);
  int*   cursors    = (int*)take(256);
  int*   offs       = (int*)take(256);

  if (off > ws_size) {
    hipMemsetAsync(d_out, 0, (size_t)out_size * 4, stream);
    return;
  }

  hipMemsetAsync(counts, 0, 256, stream);
  hipMemsetAsync(cursors, 0, 256, stream);
  hipMemsetAsync(slot_token, 0xFF, SLOT_CAP * 4, stream);

  convert_x_kernel<<<T_TOK * DIM / 1024, 256, 0, stream>>>(x, Xb);
  transpose_bf16_kernel<<<dim3(HDIM / 64, DIM / 64, NE), 256, 0, stream>>>(W1, W1T, DIM, HDIM);
  transpose_bf16_kernel<<<dim3(DIM / 64, HDIM / 64, NE), 256, 0, stream>>>(W2, W2T, HDIM, DIM);
  routing_kernel<<<T_TOK / 4, 256, 0, stream>>>(x, Wg, tok_e, tok_w, counts);
  offsets_kernel<<<1, 64, 0, stream>>>(counts, offs);
  scatter_kernel<<<T_TOK / 256, 256, 0, stream>>>(tok_e, offs, cursors, slot_token, tok_slot);
  gemm1_kernel<<<dim3(TILES_MAX, HDIM / BN), 256, 0, stream>>>(Xb, W1T, b1, slot_token, offs, Hbuf);
  gemm2_kernel<<<dim3(TILES_MAX, DIM / BN), 256, 0, stream>>>(Hbuf, W2T, b2, offs, Ybuf);
  combine_kernel<<<T_TOK, 256, 0, stream>>>(Ybuf, tok_slot, tok_w, out);
}